// Round 1
// baseline (69.115 us; speedup 1.0000x reference)
//
#include <hip/hip_runtime.h>

#define S_LEN 4096
#define DK 128
#define NPAIR (DK / 2)  // 64

// Kernel 1: extract (cos, sin) per (position, pair) from the block-diagonal R.
// cos = R[p][2k][2k], sin = R[p][2k+1][2k].  Output packed float2[S_LEN*NPAIR].
__global__ void build_cs_table(const float* __restrict__ R,
                               float2* __restrict__ cs, int total) {
    int tid = blockIdx.x * blockDim.x + threadIdx.x;
    if (tid >= total) return;
    int p = tid >> 6;   // position row 0..4095
    int k = tid & 63;   // pair index 0..63
    const float* Rr = R + (size_t)p * DK * DK;
    float c = Rr[(size_t)(2 * k) * DK + 2 * k];
    float s = Rr[(size_t)(2 * k + 1) * DK + 2 * k];
    cs[tid] = make_float2(c, s);
}

// Kernel 2: main RoPE. One float4 of x per thread-iteration = 2 rotation pairs.
// flat float4 index i = ((b*16+h)*4096 + s)*32 + j,  j in [0,32)
__global__ void rope_kernel(const float4* __restrict__ x,
                            const int* __restrict__ pos,
                            const float2* __restrict__ cs,
                            float4* __restrict__ out, long long total4) {
    long long i = (long long)blockIdx.x * blockDim.x + threadIdx.x;
    long long stride = (long long)gridDim.x * blockDim.x;
    for (; i < total4; i += stride) {
        int j = (int)(i & 31);                 // float4 slot within the 128-d row
        int s = (int)((i >> 5) & (S_LEN - 1)); // sequence position index
        int p = pos[s];
        // pairs 2j and 2j+1 -> adjacent float2s == one aligned float4
        float4 csp = *reinterpret_cast<const float4*>(
            &cs[(size_t)p * NPAIR + 2 * j]);   // (c0, s0, c1, s1)
        float4 v = x[i];
        float4 o;
        o.x = csp.x * v.x - csp.y * v.y;
        o.y = csp.y * v.x + csp.x * v.y;
        o.z = csp.z * v.z - csp.w * v.w;
        o.w = csp.w * v.z + csp.z * v.w;
        out[i] = o;
    }
}

// Fallback if workspace is too small: gather cos/sin straight from R.
__global__ void rope_gather(const float4* __restrict__ x,
                            const int* __restrict__ pos,
                            const float* __restrict__ R,
                            float4* __restrict__ out, long long total4) {
    long long i = (long long)blockIdx.x * blockDim.x + threadIdx.x;
    long long stride = (long long)gridDim.x * blockDim.x;
    for (; i < total4; i += stride) {
        int j = (int)(i & 31);
        int s = (int)((i >> 5) & (S_LEN - 1));
        int p = pos[s];
        const float* Rr = R + (size_t)p * DK * DK;
        int d0 = 4 * j;
        float c0 = Rr[(size_t)d0 * DK + d0];
        float s0 = Rr[(size_t)(d0 + 1) * DK + d0];
        float c1 = Rr[(size_t)(d0 + 2) * DK + d0 + 2];
        float s1 = Rr[(size_t)(d0 + 3) * DK + d0 + 2];
        float4 v = x[i];
        float4 o;
        o.x = c0 * v.x - s0 * v.y;
        o.y = s0 * v.x + c0 * v.y;
        o.z = c1 * v.z - s1 * v.w;
        o.w = s1 * v.z + c1 * v.w;
        out[i] = o;
    }
}

extern "C" void kernel_launch(void* const* d_in, const int* in_sizes, int n_in,
                              void* d_out, int out_size, void* d_ws, size_t ws_size,
                              hipStream_t stream) {
    const float* x = (const float*)d_in[0];
    const int* pos = (const int*)d_in[1];
    const float* R = (const float*)d_in[2];
    float* out = (float*)d_out;

    long long total = (long long)in_sizes[0];  // 4*16*4096*128 = 33,554,432
    long long total4 = total / 4;

    const size_t cs_bytes = (size_t)S_LEN * NPAIR * sizeof(float2);  // 2 MiB

    const int block = 256;
    const int grid_main = 2048;  // grid-stride; ~16 float4 per thread

    if (ws_size >= cs_bytes) {
        float2* cs = (float2*)d_ws;
        int table_total = S_LEN * NPAIR;
        build_cs_table<<<(table_total + block - 1) / block, block, 0, stream>>>(
            R, cs, table_total);
        rope_kernel<<<grid_main, block, 0, stream>>>(
            (const float4*)x, pos, cs, (float4*)out, total4);
    } else {
        rope_gather<<<grid_main, block, 0, stream>>>(
            (const float4*)x, pos, R, (float4*)out, total4);
    }
}

// Round 2
// 65.442 us; speedup vs baseline: 1.0561x; 1.0561x over previous
//
#include <hip/hip_runtime.h>

#define S_LEN 4096
#define DK 128

// Single fused RoPE kernel.
//
// Flat float4 index i = ((b*16+h)*4096 + s)*32 + j, j in [0,32).
// Grid is sized so stride = gridDim*blockDim is a multiple of 32*4096 float4s
// => each thread's (j, s) — and therefore its rotation coefficients — are
// loop-invariant. Gather (cos, -sin) once per thread from R's block diagonal
// (R[p][2k][2k] = cos and R[p][2k][2k+1] = -sin are ADJACENT -> one aligned
// float2 load per pair), then run a pure streaming loop.
__global__ void rope_kernel(const float4* __restrict__ x,
                            const int* __restrict__ pos,
                            const float* __restrict__ R,
                            float4* __restrict__ out, long long total4) {
    long long tid = (long long)blockIdx.x * blockDim.x + threadIdx.x;
    long long stride = (long long)gridDim.x * blockDim.x;

    int j = (int)(tid & 31);                 // float4 slot within 128-d row
    int s = (int)((tid >> 5) & (S_LEN - 1)); // sequence position
    int p = pos[s];

    const float* Rr = R + (size_t)p * DK * DK;
    // pairs k0 = 2j, k1 = 2j+1; diag element offset of pair k is k*2*(DK+1)
    float2 cm0 = *reinterpret_cast<const float2*>(Rr + (size_t)(4 * j) * (DK + 1));
    float2 cm1 = *reinterpret_cast<const float2*>(Rr + (size_t)(4 * j + 2) * (DK + 1));
    // cm.x = cos, cm.y = -sin

    for (long long i = tid; i < total4; i += stride) {
        float4 v = x[i];
        float4 o;
        o.x = cm0.x * v.x + cm0.y * v.y;  // cos*x0 - sin*x1
        o.y = cm0.x * v.y - cm0.y * v.x;  // sin*x0 + cos*x1
        o.z = cm1.x * v.z + cm1.y * v.w;
        o.w = cm1.x * v.w - cm1.y * v.z;
        out[i] = o;
    }
}

extern "C" void kernel_launch(void* const* d_in, const int* in_sizes, int n_in,
                              void* d_out, int out_size, void* d_ws, size_t ws_size,
                              hipStream_t stream) {
    const float* x = (const float*)d_in[0];
    const int* pos = (const int*)d_in[1];
    const float* R = (const float*)d_in[2];
    float* out = (float*)d_out;

    long long total = (long long)in_sizes[0];  // 4*16*4096*128 = 33,554,432
    long long total4 = total / 4;

    // stride MUST be a multiple of 32*4096 = 131072 float4s for the
    // loop-invariant (j, s) optimization. 2048 blocks * 256 = 524288 = 4x131072.
    const int block = 256;
    const int grid = 2048;

    rope_kernel<<<grid, block, 0, stream>>>(
        (const float4*)x, pos, R, (float4*)out, total4);
}